// Round 14
// baseline (3319.482 us; speedup 1.0000x reference)
//
#include <hip/hip_runtime.h>
#include <cstdint>
#include <cstddef>

#define B_ 16
#define S_ 512
#define H_ 768
#define L_ 12
#define NH_ 12
#define DH_ 64
#define FF_ 3072
#define NL_ 9
#define QKV_ 2304

typedef _Float16 f16x8 __attribute__((ext_vector_type(8)));
typedef _Float16 f16x4 __attribute__((ext_vector_type(4)));
typedef _Float16 f16x2 __attribute__((ext_vector_type(2)));
typedef float f32x4 __attribute__((ext_vector_type(4)));

// ---------------- async global->LDS (16B per lane, wave-uniform LDS base) ---
__device__ __forceinline__ void load_lds16(const void* g, void* l) {
  __builtin_amdgcn_global_load_lds(
      (const __attribute__((address_space(1))) unsigned int*)g,
      (__attribute__((address_space(3))) unsigned int*)l, 16, 0, 0);
}

// ---------------- block reduction helpers ----------------
__device__ __forceinline__ float block_sum256(float v, float* red) {
#pragma unroll
  for (int off = 32; off; off >>= 1) v += __shfl_down(v, off);
  __syncthreads();
  if ((threadIdx.x & 63) == 0) red[threadIdx.x >> 6] = v;
  __syncthreads();
  return red[0] + red[1] + red[2] + red[3];
}

// Fast exact-GELU: erf via Abramowitz-Stegun 7.1.26 (|err| < 1.5e-7).
__device__ __forceinline__ float gelu_f(float x) {
  float au = fabsf(x) * 0.70710678118654752f;
  float t = 1.0f / (1.0f + 0.3275911f * au);
  float p = ((((1.061405429f * t - 1.453152027f) * t + 1.421413741f) * t
              - 0.284496736f) * t + 0.254829592f) * t;
  float e = p * __expf(-au * au);
  float phi = (x >= 0.0f) ? (1.0f - 0.5f * e) : (0.5f * e);
  return x * phi;
}

// ---------------- embeddings + LayerNorm (writes f16 hb) --------------------
__global__ __launch_bounds__(256) void embed_ln_kernel(
    const int* __restrict__ wid, const int* __restrict__ tpid,
    const float* __restrict__ we, const float* __restrict__ pe,
    const float* __restrict__ te, const float* __restrict__ g,
    const float* __restrict__ bb, _Float16* __restrict__ hb) {
  __shared__ float red[4];
  int tok = blockIdx.x;
  int s = tok & (S_ - 1);
  int w = wid[tok], tp = tpid[tok];
  int t = threadIdx.x;
  float x[3];
#pragma unroll
  for (int i = 0; i < 3; ++i) {
    int j = t + i * 256;
    x[i] = we[(size_t)w * H_ + j] + pe[(size_t)s * H_ + j] + te[(size_t)tp * H_ + j];
  }
  float m = block_sum256(x[0] + x[1] + x[2], red) * (1.0f / H_);
  float d0 = x[0] - m, d1 = x[1] - m, d2 = x[2] - m;
  float var = block_sum256(d0 * d0 + d1 * d1 + d2 * d2, red) * (1.0f / H_);
  float rs = rsqrtf(var + 1e-12f);
#pragma unroll
  for (int i = 0; i < 3; ++i) {
    int j = t + i * 256;
    float v = (x[i] - m) * rs * g[j] + bb[j];
    hb[(size_t)tok * H_ + j] = (_Float16)v;
  }
}

// ---------------- LayerNorm, one wave per token (4 tokens/block) ------------
// Pure wave-shuffle reductions: no LDS, no barriers. 12 f16 per lane.
__global__ __launch_bounds__(256) void ln_f16_kernel(
    const _Float16* __restrict__ x, const float* __restrict__ g,
    const float* __restrict__ bb, _Float16* __restrict__ hb) {
  int lane = threadIdx.x & 63, wv = threadIdx.x >> 6;
  size_t tok = (size_t)blockIdx.x * 4 + wv;
  const _Float16* xr = &x[tok * H_];
  float xv[12];
#pragma unroll
  for (int i = 0; i < 3; ++i) {
    f16x4 v = *(const f16x4*)&xr[lane * 4 + i * 256];
#pragma unroll
    for (int j = 0; j < 4; ++j) xv[i * 4 + j] = (float)v[j];
  }
  float s = 0.f;
#pragma unroll
  for (int e = 0; e < 12; ++e) s += xv[e];
#pragma unroll
  for (int off = 32; off; off >>= 1) s += __shfl_xor(s, off);
  float m = s * (1.0f / H_);
  float vs = 0.f;
#pragma unroll
  for (int e = 0; e < 12; ++e) { float d = xv[e] - m; vs += d * d; }
#pragma unroll
  for (int off = 32; off; off >>= 1) vs += __shfl_xor(vs, off);
  float rs = rsqrtf(vs * (1.0f / H_) + 1e-12f);
#pragma unroll
  for (int i = 0; i < 3; ++i) {
    int j = lane * 4 + i * 256;
    float4 gv = *(const float4*)&g[j];
    float4 bv = *(const float4*)&bb[j];
    f16x4 o;
    o[0] = (_Float16)((xv[i * 4 + 0] - m) * rs * gv.x + bv.x);
    o[1] = (_Float16)((xv[i * 4 + 1] - m) * rs * gv.y + bv.y);
    o[2] = (_Float16)((xv[i * 4 + 2] - m) * rs * gv.z + bv.z);
    o[3] = (_Float16)((xv[i * 4 + 3] - m) * rs * gv.w + bv.w);
    *(f16x4*)&hb[tok * H_ + j] = o;
  }
}

// ---------------- per-layer weight convert + transpose: f32 [K][N] -> f16 [N][K]
// block 1728 additionally concats qkv bias. 64x64 tiles.
__global__ __launch_bounds__(256) void convert_weights_kernel(
    const float* __restrict__ Wq, const float* __restrict__ Wk,
    const float* __restrict__ Wv, const float* __restrict__ Wo,
    const float* __restrict__ W1, const float* __restrict__ W2,
    _Float16* __restrict__ qT, _Float16* __restrict__ kT,
    _Float16* __restrict__ vT, _Float16* __restrict__ oT,
    _Float16* __restrict__ w1T, _Float16* __restrict__ w2T,
    const float* __restrict__ bq, const float* __restrict__ bk,
    const float* __restrict__ bv, float* __restrict__ qkvb) {
  int id = blockIdx.x;
  int tid = threadIdx.x;
  if (id == 1728) {  // bias concat
    for (int j = tid; j < H_; j += 256) {
      qkvb[j] = bq[j];
      qkvb[H_ + j] = bk[j];
      qkvb[2 * H_ + j] = bv[j];
    }
    return;
  }
  __shared__ float T[64][65];
  const float* src;
  _Float16* dst;
  int K, N, tk, tn;
  if (id < 576) {
    int mat = id / 144, t = id % 144;
    K = 768; N = 768; tk = t / 12; tn = t % 12;
    src = (mat == 0) ? Wq : (mat == 1) ? Wk : (mat == 2) ? Wv : Wo;
    dst = (mat == 0) ? qT : (mat == 1) ? kT : (mat == 2) ? vT : oT;
  } else if (id < 1152) {
    int t = id - 576; K = 768; N = 3072; tk = t / 48; tn = t % 48;
    src = W1; dst = w1T;
  } else {
    int t = id - 1152; K = 3072; N = 768; tk = t / 12; tn = t % 12;
    src = W2; dst = w2T;
  }
  int k0 = tk * 64, n0 = tn * 64;
  {
    int r = tid >> 4, c4 = (tid & 15) * 4;
#pragma unroll
    for (int i = 0; i < 4; ++i) {
      float4 v = *(const float4*)&src[(size_t)(k0 + r + i * 16) * N + n0 + c4];
      T[r + i * 16][c4 + 0] = v.x;
      T[r + i * 16][c4 + 1] = v.y;
      T[r + i * 16][c4 + 2] = v.z;
      T[r + i * 16][c4 + 3] = v.w;
    }
  }
  __syncthreads();
#pragma unroll
  for (int i = 0; i < 2; ++i) {
    int chunk = tid + i * 256;
    int n = chunk >> 3, kc = (chunk & 7) * 8;
    f16x8 o;
#pragma unroll
    for (int j = 0; j < 8; ++j) o[j] = (_Float16)T[kc + j][n];
    *(f16x8*)&dst[(size_t)(n0 + n) * K + k0 + kc] = o;
  }
}

// ---------------- attn mask bias precompute (layer-invariant) ---------------
__global__ void maskbias_kernel(const int* __restrict__ mask, float* __restrict__ bz) {
  int i = blockIdx.x * 256 + threadIdx.x;
  const float C = 0.125f * 1.44269504088896f;
  bz[i] = (1.0f - (float)mask[i]) * (-1e9f * C);
}

// ---------------- f16 MFMA GEMM, 2-phase dbuf, BM=128, BK=64 (r9, proven) ---
// OUT: 1 = f16+bias, 2 = f16+bias+GELU, 3 = f16+bias+residual(hres f16)
template <int OUT>
__global__ __launch_bounds__(256) void gemm_f16(
    const _Float16* __restrict__ A, const _Float16* __restrict__ Bt,
    const float* __restrict__ bias, void* __restrict__ Cv,
    int M, int N, int K, const _Float16* __restrict__ hres) {
  __shared__ _Float16 As[2][128 * 64];
  __shared__ _Float16 Bs[2][128 * 64];
  int tid = threadIdx.x;
  int lane = tid & 63, w = tid >> 6;
  int wr = w >> 1, wc = w & 1;
  int l15 = lane & 15, kb = lane >> 4;
  int swr = l15 & 7;

  int nwg = gridDim.x * gridDim.y;
  int bid = blockIdx.y * gridDim.x + blockIdx.x;
  int swz = bid;
  if ((nwg & 7) == 0) {
    int cpx = nwg >> 3;
    swz = (bid & 7) * cpx + (bid >> 3);
  }
  int bx = swz % gridDim.x, by = swz / gridDim.x;
  int row0 = by * 128, col0 = bx * 128;

  int drow = lane >> 3;
  int schunk = (lane & 7) ^ drow;
  const _Float16* gA = A + (size_t)(row0 + w * 32 + drow) * K + schunk * 8;
  const _Float16* gB = Bt + (size_t)(col0 + w * 32 + drow) * K + schunk * 8;

  auto STAGE = [&](int t, int buf) {
    int ko = t * 64;
#pragma unroll
    for (int j = 0; j < 4; ++j) {
      load_lds16(gA + (size_t)(j * 8) * K + ko,
                 (char*)&As[buf][0] + (w * 32 + j * 8) * 128);
      load_lds16(gB + (size_t)(j * 8) * K + ko,
                 (char*)&Bs[buf][0] + (w * 32 + j * 8) * 128);
    }
  };

  f32x4 acc[4][4] = {};
  int nk = K >> 6;

  STAGE(0, 0);
  __syncthreads();

  for (int kt = 0; kt < nk; ++kt) {
    int cur = kt & 1;
    if (kt + 1 < nk) STAGE(kt + 1, cur ^ 1);
#pragma unroll
    for (int ks = 0; ks < 2; ++ks) {
      f16x8 af[4], bf[4];
      int rpos = ((ks * 4 + kb) ^ swr) * 8;
#pragma unroll
      for (int m = 0; m < 4; ++m)
        af[m] = *(const f16x8*)&As[cur][(wr * 64 + m * 16 + l15) * 64 + rpos];
#pragma unroll
      for (int n = 0; n < 4; ++n)
        bf[n] = *(const f16x8*)&Bs[cur][(wc * 64 + n * 16 + l15) * 64 + rpos];
#pragma unroll
      for (int m = 0; m < 4; ++m)
#pragma unroll
        for (int n = 0; n < 4; ++n)
          acc[m][n] = __builtin_amdgcn_mfma_f32_16x16x32_f16(af[m], bf[n], acc[m][n], 0, 0, 0);
    }
    __syncthreads();
  }
#pragma unroll
  for (int n = 0; n < 4; ++n) {
    int col = col0 + wc * 64 + n * 16 + l15;
    float bv = bias[col];
#pragma unroll
    for (int m = 0; m < 4; ++m) {
      int rowb = row0 + wr * 64 + m * 16 + kb * 4;
#pragma unroll
      for (int r = 0; r < 4; ++r) {
        float v = acc[m][n][r] + bv;
        if (OUT == 2) v = gelu_f(v);
        if (OUT == 3) v += (float)hres[(size_t)(rowb + r) * N + col];
        ((_Float16*)Cv)[(size_t)(rowb + r) * N + col] = (_Float16)v;
      }
    }
  }
}

// ---------------- f16 MFMA GEMM, BM=64 x BN=128, BK=64, 128 threads ---------
// Same 2-phase schedule/swizzle; 48KB LDS -> 3 blocks/CU. QKV (2304 blocks =
// 3 exact rounds) and N=768 GEMMs (768 blocks = 1 full round).
template <int OUT>
__global__ __launch_bounds__(128) void gemm64(
    const _Float16* __restrict__ A, const _Float16* __restrict__ Bt,
    const float* __restrict__ bias, void* __restrict__ Cv,
    int M, int N, int K, const _Float16* __restrict__ hres) {
  __shared__ _Float16 As[2][64 * 64];
  __shared__ _Float16 Bs[2][128 * 64];
  int tid = threadIdx.x;
  int lane = tid & 63, w = tid >> 6;  // w in {0,1}
  int l15 = lane & 15, kb = lane >> 4;
  int swr = l15 & 7;

  int nwg = gridDim.x * gridDim.y;
  int bid = blockIdx.y * gridDim.x + blockIdx.x;
  int swz = bid;
  if ((nwg & 7) == 0) {
    int cpx = nwg >> 3;
    swz = (bid & 7) * cpx + (bid >> 3);
  }
  int bx = swz % gridDim.x, by = swz / gridDim.x;
  int row0 = by * 64, col0 = bx * 128;

  int drow = lane >> 3;
  int schunk = (lane & 7) ^ drow;
  const _Float16* gA = A + (size_t)(row0 + w * 32 + drow) * K + schunk * 8;
  const _Float16* gB = Bt + (size_t)(col0 + w * 64 + drow) * K + schunk * 8;

  auto STAGE = [&](int t, int buf) {
    int ko = t * 64;
#pragma unroll
    for (int j = 0; j < 4; ++j)
      load_lds16(gA + (size_t)(j * 8) * K + ko,
                 (char*)&As[buf][0] + (w * 32 + j * 8) * 128);
#pragma unroll
    for (int j = 0; j < 8; ++j)
      load_lds16(gB + (size_t)(j * 8) * K + ko,
                 (char*)&Bs[buf][0] + (w * 64 + j * 8) * 128);
  };

  f32x4 acc[4][4] = {};
  int nk = K >> 6;

  STAGE(0, 0);
  __syncthreads();

  for (int kt = 0; kt < nk; ++kt) {
    int cur = kt & 1;
    if (kt + 1 < nk) STAGE(kt + 1, cur ^ 1);
#pragma unroll
    for (int ks = 0; ks < 2; ++ks) {
      f16x8 af[4], bf[4];
      int rpos = ((ks * 4 + kb) ^ swr) * 8;
#pragma unroll
      for (int m = 0; m < 4; ++m)
        af[m] = *(const f16x8*)&As[cur][(m * 16 + l15) * 64 + rpos];
#pragma unroll
      for (int n = 0; n < 4; ++n)
        bf[n] = *(const f16x8*)&Bs[cur][(w * 64 + n * 16 + l15) * 64 + rpos];
#pragma unroll
      for (int m = 0; m < 4; ++m)
#pragma unroll
        for (int n = 0; n < 4; ++n)
          acc[m][n] = __builtin_amdgcn_mfma_f32_16x16x32_f16(af[m], bf[n], acc[m][n], 0, 0, 0);
    }
    __syncthreads();
  }
#pragma unroll
  for (int n = 0; n < 4; ++n) {
    int col = col0 + w * 64 + n * 16 + l15;
    float bv = bias[col];
#pragma unroll
    for (int m = 0; m < 4; ++m) {
      int rowb = row0 + m * 16 + kb * 4;
#pragma unroll
      for (int r = 0; r < 4; ++r) {
        float v = acc[m][n][r] + bv;
        if (OUT == 2) v = gelu_f(v);
        if (OUT == 3) v += (float)hres[(size_t)(rowb + r) * N + col];
        ((_Float16*)Cv)[(size_t)(rowb + r) * N + col] = (_Float16)v;
      }
    }
  }
}

// ---------------- V transpose per head: qkv v-cols -> vt [b*12+h][64][512] --
__global__ __launch_bounds__(256) void vtrans_kernel(
    const _Float16* __restrict__ v, int RS, _Float16* __restrict__ vt) {
  __shared__ _Float16 T[64][72];
  int s0 = blockIdx.x * 64;
  int bh = blockIdx.y;
  int b = bh / NH_, h = bh % NH_;
  int tid = threadIdx.x;
#pragma unroll
  for (int i = 0; i < 2; ++i) {
    int chunk = tid + i * 256;
    int s = chunk >> 3, dc = (chunk & 7) * 8;
    *(f16x8*)&T[s][dc] = *(const f16x8*)&v[(size_t)(b * S_ + s0 + s) * RS + h * DH_ + dc];
  }
  __syncthreads();
#pragma unroll
  for (int i = 0; i < 2; ++i) {
    int chunk = tid + i * 256;
    int d = chunk >> 3, sc = (chunk & 7) * 8;
    f16x8 o;
#pragma unroll
    for (int j = 0; j < 8; ++j) o[j] = T[sc + j][d];
    *(f16x8*)&vt[(size_t)(bh * DH_ + d) * S_ + s0 + sc] = o;
  }
}

// ---------------- fused flash attention, f16 MFMA, paired q-tiles -----------
// grid (4 q-pairs, 12 heads, 16 batch) = 768 blocks. biasz read from global
// (L2-hot) instead of LDS: LDS = 53,248B <= 160KB/3 -> 3 blocks/CU candidate
// (one full co-residency round, no tail).
__global__ __launch_bounds__(256) void flash_attn_kernel(
    const _Float16* __restrict__ q, const _Float16* __restrict__ k,
    const _Float16* __restrict__ vt, int RS, const float* __restrict__ biasz_g,
    _Float16* __restrict__ ctx) {
  __shared__ _Float16 Ks[128 * 72];
  __shared__ _Float16 Vs[64 * 136];
  __shared__ _Float16 Ps[4][16 * 136];
  int qt = blockIdx.x, h = blockIdx.y, b = blockIdx.z;
  int tid = threadIdx.x, lane = tid & 63, w = tid >> 6;
  int l15 = lane & 15, kb = lane >> 4;
  const float C = 0.125f * 1.44269504088896f;

  f16x8 qf[2][2];
#pragma unroll
  for (int hh = 0; hh < 2; ++hh) {
    int qrow = b * S_ + qt * 128 + hh * 64 + w * 16 + l15;
    qf[hh][0] = *(const f16x8*)&q[(size_t)qrow * RS + h * DH_ + kb * 8];
    qf[hh][1] = *(const f16x8*)&q[(size_t)qrow * RS + h * DH_ + 32 + kb * 8];
  }

  auto loadKV = [&](int kt, f16x8* rk, f16x8* rv) {
#pragma unroll
    for (int i = 0; i < 4; ++i) {
      int idx = tid + i * 256;
      int r = idx >> 3, c = idx & 7;
      rk[i] = *(const f16x8*)&k[(size_t)(b * S_ + kt * 128 + r) * RS + h * DH_ + c * 8];
      int d = idx >> 4, c2 = idx & 15;
      rv[i] = *(const f16x8*)&vt[(size_t)((b * NH_ + h) * DH_ + d) * S_ + kt * 128 + c2 * 8];
    }
  };

  float m_run[2][4], l_run[2][4];
  f32x4 o[2][4] = {};
#pragma unroll
  for (int hh = 0; hh < 2; ++hh)
#pragma unroll
    for (int r = 0; r < 4; ++r) { m_run[hh][r] = -1e30f; l_run[hh][r] = 0.f; }

  f16x8 rk[4], rv[4];
  loadKV(0, rk, rv);
  for (int kt = 0; kt < 4; ++kt) {
    __syncthreads();
#pragma unroll
    for (int i = 0; i < 4; ++i) {
      int idx = tid + i * 256;
      int r = idx >> 3, c = idx & 7;
      *(f16x8*)&Ks[r * 72 + c * 8] = rk[i];
      int d = idx >> 4, c2 = idx & 15;
      *(f16x8*)&Vs[d * 136 + c2 * 8] = rv[i];
    }
    __syncthreads();
    if (kt < 3) loadKV(kt + 1, rk, rv);
    float zb[8];
#pragma unroll
    for (int nf = 0; nf < 8; ++nf)
      zb[nf] = biasz_g[b * S_ + kt * 128 + nf * 16 + l15];
#pragma unroll
    for (int hh = 0; hh < 2; ++hh) {
      f32x4 s[8];
#pragma unroll
      for (int nf = 0; nf < 8; ++nf) {
        f16x8 b0 = *(const f16x8*)&Ks[(nf * 16 + l15) * 72 + kb * 8];
        f16x8 b1 = *(const f16x8*)&Ks[(nf * 16 + l15) * 72 + 32 + kb * 8];
        f32x4 z = {};
        z = __builtin_amdgcn_mfma_f32_16x16x32_f16(qf[hh][0], b0, z, 0, 0, 0);
        z = __builtin_amdgcn_mfma_f32_16x16x32_f16(qf[hh][1], b1, z, 0, 0, 0);
        s[nf] = z;
      }
      float pw[8][4];
      float corr[4];
#pragma unroll
      for (int r = 0; r < 4; ++r) {
        float mx = -1e30f;
#pragma unroll
        for (int nf = 0; nf < 8; ++nf) mx = fmaxf(mx, s[nf][r] * C + zb[nf]);
#pragma unroll
        for (int d = 1; d < 16; d <<= 1) mx = fmaxf(mx, __shfl_xor(mx, d));
        float mnew = fmaxf(m_run[hh][r], mx);
        float cr = exp2f(m_run[hh][r] - mnew);
        m_run[hh][r] = mnew;
        corr[r] = cr;
        float sum = 0.f;
#pragma unroll
        for (int nf = 0; nf < 8; ++nf) {
          float pv = exp2f(s[nf][r] * C + zb[nf] - mnew);
          pw[nf][r] = pv;
          sum += pv;
        }
#pragma unroll
        for (int d = 1; d < 16; d <<= 1) sum += __shfl_xor(sum, d);
        l_run[hh][r] = l_run[hh][r] * cr + sum;
      }
#pragma unroll
      for (int nf2 = 0; nf2 < 4; ++nf2)
#pragma unroll
        for (int r = 0; r < 4; ++r) o[hh][nf2][r] *= corr[r];
#pragma unroll
      for (int nf = 0; nf < 8; ++nf)
#pragma unroll
        for (int r = 0; r < 4; ++r)
          Ps[w][(kb * 4 + r) * 136 + nf * 16 + l15] = (_Float16)pw[nf][r];
      // Ps is wave-private; within-wave ds write->read ordering handled by
      // compiler-inserted lgkmcnt waits.
#pragma unroll
      for (int ks = 0; ks < 4; ++ks) {
        f16x8 pa = *(const f16x8*)&Ps[w][l15 * 136 + ks * 32 + kb * 8];
#pragma unroll
        for (int nf2 = 0; nf2 < 4; ++nf2) {
          f16x8 vb2 = *(const f16x8*)&Vs[(nf2 * 16 + l15) * 136 + ks * 32 + kb * 8];
          o[hh][nf2] = __builtin_amdgcn_mfma_f32_16x16x32_f16(pa, vb2, o[hh][nf2], 0, 0, 0);
        }
      }
    }
  }
#pragma unroll
  for (int hh = 0; hh < 2; ++hh) {
    float inv[4];
#pragma unroll
    for (int r = 0; r < 4; ++r) inv[r] = 1.0f / fmaxf(l_run[hh][r], 1e-37f);
#pragma unroll
    for (int nf2 = 0; nf2 < 4; ++nf2)
#pragma unroll
      for (int r = 0; r < 4; ++r) {
        int row = b * S_ + qt * 128 + hh * 64 + w * 16 + kb * 4 + r;
        ctx[(size_t)row * H_ + h * DH_ + nf2 * 16 + l15] = (_Float16)(o[hh][nf2][r] * inv[r]);
      }
  }
}

// ---------------- valid-token compaction: parallel stable prefix scan -------
__global__ __launch_bounds__(512) void compact_idx_kernel(
    const int* __restrict__ valid, int* __restrict__ src_of) {
  __shared__ int wsum[8];
  int b = blockIdx.x;
  int t = threadIdx.x;
  int lane = t & 63, wv = t >> 6;
  int v = valid[b * S_ + t];
  unsigned long long ball = __ballot(v != 0);
  int pre = __popcll(ball & ((1ULL << lane) - 1ULL));
  if (lane == 0) wsum[wv] = __popcll(ball);
  src_of[b * S_ + t] = -1;  // fill; scatter below overwrites valid slots
  __syncthreads();
  int base = 0;
#pragma unroll
  for (int i = 0; i < 8; ++i) base += (i < wv) ? wsum[i] : 0;
  if (v) src_of[b * S_ + base + pre] = b * S_ + t;
}

// ---------------- classifier + softmax: one wave per output token -----------
__global__ __launch_bounds__(256) void cls_kernel(
    const _Float16* __restrict__ hb, const int* __restrict__ src_of,
    const float* __restrict__ W, const float* __restrict__ bias2,
    float* __restrict__ out) {
  int lane = threadIdx.x & 63, wv = threadIdx.x >> 6;
  int tok = blockIdx.x * 4 + wv;
  int src = src_of[tok];
  float acc[NL_] = {};
  if (src >= 0) {
    for (int h0 = lane * 2; h0 < H_; h0 += 128) {
      f16x2 xv = *(const f16x2*)&hb[(size_t)src * H_ + h0];
      float x0 = (float)xv[0], x1 = (float)xv[1];
#pragma unroll
      for (int n = 0; n < NL_; ++n)
        acc[n] = fmaf(x0, W[h0 * NL_ + n], fmaf(x1, W[(h0 + 1) * NL_ + n], acc[n]));
    }
  }
#pragma unroll
  for (int n = 0; n < NL_; ++n) {
#pragma unroll
    for (int off = 32; off; off >>= 1) acc[n] += __shfl_down(acc[n], off);
  }
  if (lane == 0) {
    float vls[NL_], mx = -1e30f;
#pragma unroll
    for (int n = 0; n < NL_; ++n) {
      vls[n] = acc[n] + bias2[n];
      mx = fmaxf(mx, vls[n]);
    }
    float s = 0.f;
#pragma unroll
    for (int n = 0; n < NL_; ++n) {
      vls[n] = expf(vls[n] - mx);
      s += vls[n];
    }
    float inv = 1.0f / s;
#pragma unroll
    for (int n = 0; n < NL_; ++n) out[(size_t)tok * NL_ + n] = vls[n] * inv;
  }
}

extern "C" void kernel_launch(void* const* d_in, const int* in_sizes, int n_in,
                              void* d_out, int out_size, void* d_ws, size_t ws_size,
                              hipStream_t stream) {
  const int* wid = (const int*)d_in[0];
  const int* mask = (const int*)d_in[1];
  const int* tpid = (const int*)d_in[2];
  const int* valid = (const int*)d_in[3];
  const float* we = (const float*)d_in[4];
  const float* pe = (const float*)d_in[5];
  const float* te = (const float*)d_in[6];
  const float* eg = (const float*)d_in[7];
  const float* eb = (const float*)d_in[8];
  const float* Wq = (const float*)d_in[9];
  const float* bq = (const float*)d_in[10];
  const float* Wk = (const float*)d_in[11];
  const float* bk = (const float*)d_in[12];
  const float* Wv = (const float*)d_in[13];
  const float* bv = (const float*)d_in[14];
  const float* Wo = (const float*)d_in[15];
  const float* bo = (const float*)d_in[16];
  const float* g1 = (const float*)d_in[17];
  const float* gb1 = (const float*)d_in[18];
  const float* W1 = (const float*)d_in[19];
  const float* bf1 = (const float*)d_in[20];
  const float* W2 = (const float*)d_in[21];
  const float* bf2 = (const float*)d_in[22];
  const float* g2 = (const float*)d_in[23];
  const float* gb2 = (const float*)d_in[24];
  const float* cW = (const float*)d_in[25];
  const float* cb = (const float*)d_in[26];
  float* out = (float*)d_out;

  const size_t TOK = (size_t)B_ * S_;  // 8192
  char* ws = (char*)d_ws;
  _Float16* hb = (_Float16*)(ws + 25165824);          // 12,582,912 B (residual stream)
  _Float16* t1h = (_Float16*)(ws + 37748736);         // 12,582,912 B (x = delta+res, f16)
  char* un1 = ws + 62914560;                          // 50,331,648 B union
  _Float16* qkv = (_Float16*)un1;                     // [8192][2304] = 37,748,736 B
  _Float16* vt = (_Float16*)(un1 + 37748736);         // 12,582,912 B
  _Float16* ffh = (_Float16*)un1;                     // overlays qkv/vt after attn
  _Float16* ctx = (_Float16*)(ws + 113246208);        // 12,582,912 B
  char* wbuf = ws + 125829120;                        // 14,155,776 B
  _Float16* wqT = (_Float16*)wbuf;                    // [2304][768] fused (q,k,v rows)
  _Float16* wkT = (_Float16*)(wbuf + 1179648);
  _Float16* wvT = (_Float16*)(wbuf + 2359296);
  _Float16* woT = (_Float16*)(wbuf + 3538944);
  _Float16* w1T = (_Float16*)(wbuf + 4718592);
  _Float16* w2T = (_Float16*)(wbuf + 9437184);
  int* src_of = (int*)(ws + 139984896);               // 32,768 B
  float* qkvb = (float*)(ws + 140017664);             // 9,216 B
  float* biasz_g = (float*)(ws + 140026880);          // 32,768 B

  dim3 blk(256);
  dim3 blk128(128);
  embed_ln_kernel<<<dim3((unsigned)TOK), blk, 0, stream>>>(wid, tpid, we, pe, te, eg, eb, hb);
  maskbias_kernel<<<dim3((unsigned)(TOK / 256)), blk, 0, stream>>>(mask, biasz_g);

  dim3 gQKV64(QKV_ / 128, TOK / 64);  // (18, 128) = 2304 blocks = 3 exact rounds @3/CU
  dim3 gH64(H_ / 128, TOK / 64);      // (6, 128)  = 768 blocks  = 1 round, all co-resident
  dim3 gF(FF_ / 128, TOK / 128);      // (24, 64)  = 1536 blocks = 3 exact rounds @2/CU
  dim3 gLN((unsigned)(TOK / 4));      // wave-per-token LN
  for (int l = 0; l < L_; ++l) {
    convert_weights_kernel<<<dim3(1729), blk, 0, stream>>>(
        Wq + (size_t)l * H_ * H_, Wk + (size_t)l * H_ * H_,
        Wv + (size_t)l * H_ * H_, Wo + (size_t)l * H_ * H_,
        W1 + (size_t)l * H_ * FF_, W2 + (size_t)l * FF_ * H_,
        wqT, wkT, wvT, woT, w1T, w2T,
        bq + l * H_, bk + l * H_, bv + l * H_, qkvb);
    gemm64<1><<<gQKV64, blk128, 0, stream>>>(hb, wqT, qkvb, qkv, (int)TOK, QKV_, H_, nullptr);
    vtrans_kernel<<<dim3(S_ / 64, B_ * NH_), blk, 0, stream>>>(qkv + 2 * H_, QKV_, vt);
    flash_attn_kernel<<<dim3(S_ / 128, NH_, B_), blk, 0, stream>>>(
        qkv, qkv + H_, vt, QKV_, biasz_g, ctx);
    // x = ctx @ Wo + bo + hb  (f16)
    gemm64<3><<<gH64, blk128, 0, stream>>>(ctx, woT, bo + l * H_, t1h, (int)TOK, H_, H_, hb);
    ln_f16_kernel<<<gLN, blk, 0, stream>>>(t1h, g1 + l * H_, gb1 + l * H_, hb);
    gemm_f16<2><<<gF, blk, 0, stream>>>(hb, w1T, bf1 + l * FF_, ffh, (int)TOK, FF_, H_, nullptr);
    // x = ffh @ W2 + b2 + hb  (f16)
    gemm64<3><<<gH64, blk128, 0, stream>>>(ffh, w2T, bf2 + l * H_, t1h, (int)TOK, H_, FF_, hb);
    ln_f16_kernel<<<gLN, blk, 0, stream>>>(t1h, g2 + l * H_, gb2 + l * H_, hb);
  }

  compact_idx_kernel<<<dim3(B_), dim3(512), 0, stream>>>(valid, src_of);
  cls_kernel<<<dim3((unsigned)(TOK / 4)), blk, 0, stream>>>(hb, src_of, cW, cb, out);
}

// Round 15
// 3308.361 us; speedup vs baseline: 1.0034x; 1.0034x over previous
//
#include <hip/hip_runtime.h>
#include <cstdint>
#include <cstddef>

#define B_ 16
#define S_ 512
#define H_ 768
#define L_ 12
#define NH_ 12
#define DH_ 64
#define FF_ 3072
#define NL_ 9
#define QKV_ 2304

typedef _Float16 f16x8 __attribute__((ext_vector_type(8)));
typedef _Float16 f16x4 __attribute__((ext_vector_type(4)));
typedef _Float16 f16x2 __attribute__((ext_vector_type(2)));
typedef float f32x4 __attribute__((ext_vector_type(4)));

// ---------------- async global->LDS (16B per lane, wave-uniform LDS base) ---
__device__ __forceinline__ void load_lds16(const void* g, void* l) {
  __builtin_amdgcn_global_load_lds(
      (const __attribute__((address_space(1))) unsigned int*)g,
      (__attribute__((address_space(3))) unsigned int*)l, 16, 0, 0);
}

// ---------------- block reduction helpers ----------------
__device__ __forceinline__ float block_sum256(float v, float* red) {
#pragma unroll
  for (int off = 32; off; off >>= 1) v += __shfl_down(v, off);
  __syncthreads();
  if ((threadIdx.x & 63) == 0) red[threadIdx.x >> 6] = v;
  __syncthreads();
  return red[0] + red[1] + red[2] + red[3];
}

// 192-thread (3-wave) block sum
__device__ __forceinline__ float block_sum192(float v, float* red) {
#pragma unroll
  for (int off = 32; off; off >>= 1) v += __shfl_down(v, off);
  __syncthreads();
  if ((threadIdx.x & 63) == 0) red[threadIdx.x >> 6] = v;
  __syncthreads();
  return red[0] + red[1] + red[2];
}

// Fast exact-GELU: erf via Abramowitz-Stegun 7.1.26 (|err| < 1.5e-7).
__device__ __forceinline__ float gelu_f(float x) {
  float au = fabsf(x) * 0.70710678118654752f;
  float t = 1.0f / (1.0f + 0.3275911f * au);
  float p = ((((1.061405429f * t - 1.453152027f) * t + 1.421413741f) * t
              - 0.284496736f) * t + 0.254829592f) * t;
  float e = p * __expf(-au * au);
  float phi = (x >= 0.0f) ? (1.0f - 0.5f * e) : (0.5f * e);
  return x * phi;
}

// ---------------- embeddings + LayerNorm (writes f16 hb) --------------------
__global__ __launch_bounds__(256) void embed_ln_kernel(
    const int* __restrict__ wid, const int* __restrict__ tpid,
    const float* __restrict__ we, const float* __restrict__ pe,
    const float* __restrict__ te, const float* __restrict__ g,
    const float* __restrict__ bb, _Float16* __restrict__ hb) {
  __shared__ float red[4];
  int tok = blockIdx.x;
  int s = tok & (S_ - 1);
  int w = wid[tok], tp = tpid[tok];
  int t = threadIdx.x;
  float x[3];
#pragma unroll
  for (int i = 0; i < 3; ++i) {
    int j = t + i * 256;
    x[i] = we[(size_t)w * H_ + j] + pe[(size_t)s * H_ + j] + te[(size_t)tp * H_ + j];
  }
  float m = block_sum256(x[0] + x[1] + x[2], red) * (1.0f / H_);
  float d0 = x[0] - m, d1 = x[1] - m, d2 = x[2] - m;
  float var = block_sum256(d0 * d0 + d1 * d1 + d2 * d2, red) * (1.0f / H_);
  float rs = rsqrtf(var + 1e-12f);
#pragma unroll
  for (int i = 0; i < 3; ++i) {
    int j = t + i * 256;
    float v = (x[i] - m) * rs * g[j] + bb[j];
    hb[(size_t)tok * H_ + j] = (_Float16)v;
  }
}

// ---------------- pure LayerNorm on f16 x -> f16 hb (192 thr, f16x4) --------
__global__ __launch_bounds__(192) void ln_f16_kernel(
    const _Float16* __restrict__ x, const float* __restrict__ g,
    const float* __restrict__ bb, _Float16* __restrict__ hb) {
  __shared__ float red[3];
  int tok = blockIdx.x;
  int t = threadIdx.x;
  int j = t * 4;
  f16x4 xv = *(const f16x4*)&x[(size_t)tok * H_ + j];
  float v0 = (float)xv[0], v1 = (float)xv[1], v2 = (float)xv[2], v3 = (float)xv[3];
  float m = block_sum192(v0 + v1 + v2 + v3, red) * (1.0f / H_);
  float d0 = v0 - m, d1 = v1 - m, d2 = v2 - m, d3 = v3 - m;
  __syncthreads();  // red reuse
  float var = block_sum192(d0 * d0 + d1 * d1 + d2 * d2 + d3 * d3, red) * (1.0f / H_);
  float rs = rsqrtf(var + 1e-12f);
  float4 gv = *(const float4*)&g[j];
  float4 bv = *(const float4*)&bb[j];
  f16x4 o;
  o[0] = (_Float16)(d0 * rs * gv.x + bv.x);
  o[1] = (_Float16)(d1 * rs * gv.y + bv.y);
  o[2] = (_Float16)(d2 * rs * gv.z + bv.z);
  o[3] = (_Float16)(d3 * rs * gv.w + bv.w);
  *(f16x4*)&hb[(size_t)tok * H_ + j] = o;
}

// ---------------- per-layer weight convert + transpose: f32 [K][N] -> f16 [N][K]
// block 1728 additionally concats qkv bias. 64x64 tiles.
__global__ __launch_bounds__(256) void convert_weights_kernel(
    const float* __restrict__ Wq, const float* __restrict__ Wk,
    const float* __restrict__ Wv, const float* __restrict__ Wo,
    const float* __restrict__ W1, const float* __restrict__ W2,
    _Float16* __restrict__ qT, _Float16* __restrict__ kT,
    _Float16* __restrict__ vT, _Float16* __restrict__ oT,
    _Float16* __restrict__ w1T, _Float16* __restrict__ w2T,
    const float* __restrict__ bq, const float* __restrict__ bk,
    const float* __restrict__ bv, float* __restrict__ qkvb) {
  int id = blockIdx.x;
  int tid = threadIdx.x;
  if (id == 1728) {  // bias concat
    for (int j = tid; j < H_; j += 256) {
      qkvb[j] = bq[j];
      qkvb[H_ + j] = bk[j];
      qkvb[2 * H_ + j] = bv[j];
    }
    return;
  }
  __shared__ float T[64][65];
  const float* src;
  _Float16* dst;
  int K, N, tk, tn;
  if (id < 576) {
    int mat = id / 144, t = id % 144;
    K = 768; N = 768; tk = t / 12; tn = t % 12;
    src = (mat == 0) ? Wq : (mat == 1) ? Wk : (mat == 2) ? Wv : Wo;
    dst = (mat == 0) ? qT : (mat == 1) ? kT : (mat == 2) ? vT : oT;
  } else if (id < 1152) {
    int t = id - 576; K = 768; N = 3072; tk = t / 48; tn = t % 48;
    src = W1; dst = w1T;
  } else {
    int t = id - 1152; K = 3072; N = 768; tk = t / 12; tn = t % 12;
    src = W2; dst = w2T;
  }
  int k0 = tk * 64, n0 = tn * 64;
  {
    int r = tid >> 4, c4 = (tid & 15) * 4;
#pragma unroll
    for (int i = 0; i < 4; ++i) {
      float4 v = *(const float4*)&src[(size_t)(k0 + r + i * 16) * N + n0 + c4];
      T[r + i * 16][c4 + 0] = v.x;
      T[r + i * 16][c4 + 1] = v.y;
      T[r + i * 16][c4 + 2] = v.z;
      T[r + i * 16][c4 + 3] = v.w;
    }
  }
  __syncthreads();
#pragma unroll
  for (int i = 0; i < 2; ++i) {
    int chunk = tid + i * 256;
    int n = chunk >> 3, kc = (chunk & 7) * 8;
    f16x8 o;
#pragma unroll
    for (int j = 0; j < 8; ++j) o[j] = (_Float16)T[kc + j][n];
    *(f16x8*)&dst[(size_t)(n0 + n) * K + k0 + kc] = o;
  }
}

// ---------------- attn mask bias precompute (layer-invariant) ---------------
__global__ void maskbias_kernel(const int* __restrict__ mask, float* __restrict__ bz) {
  int i = blockIdx.x * 256 + threadIdx.x;
  const float C = 0.125f * 1.44269504088896f;
  bz[i] = (1.0f - (float)mask[i]) * (-1e9f * C);
}

// ---------------- f16 MFMA GEMM, 2-phase dbuf, BM=128, BK=64 (r9, proven) ---
// OUT: 1 = f16+bias, 2 = f16+bias+GELU, 3 = f16+bias+residual(hres f16)
template <int OUT>
__global__ __launch_bounds__(256) void gemm_f16(
    const _Float16* __restrict__ A, const _Float16* __restrict__ Bt,
    const float* __restrict__ bias, void* __restrict__ Cv,
    int M, int N, int K, const _Float16* __restrict__ hres) {
  __shared__ _Float16 As[2][128 * 64];
  __shared__ _Float16 Bs[2][128 * 64];
  int tid = threadIdx.x;
  int lane = tid & 63, w = tid >> 6;
  int wr = w >> 1, wc = w & 1;
  int l15 = lane & 15, kb = lane >> 4;
  int swr = l15 & 7;

  int nwg = gridDim.x * gridDim.y;
  int bid = blockIdx.y * gridDim.x + blockIdx.x;
  int swz = bid;
  if ((nwg & 7) == 0) {
    int cpx = nwg >> 3;
    swz = (bid & 7) * cpx + (bid >> 3);
  }
  int bx = swz % gridDim.x, by = swz / gridDim.x;
  int row0 = by * 128, col0 = bx * 128;

  int drow = lane >> 3;
  int schunk = (lane & 7) ^ drow;
  const _Float16* gA = A + (size_t)(row0 + w * 32 + drow) * K + schunk * 8;
  const _Float16* gB = Bt + (size_t)(col0 + w * 32 + drow) * K + schunk * 8;

  auto STAGE = [&](int t, int buf) {
    int ko = t * 64;
#pragma unroll
    for (int j = 0; j < 4; ++j) {
      load_lds16(gA + (size_t)(j * 8) * K + ko,
                 (char*)&As[buf][0] + (w * 32 + j * 8) * 128);
      load_lds16(gB + (size_t)(j * 8) * K + ko,
                 (char*)&Bs[buf][0] + (w * 32 + j * 8) * 128);
    }
  };

  f32x4 acc[4][4] = {};
  int nk = K >> 6;

  STAGE(0, 0);
  __syncthreads();

  for (int kt = 0; kt < nk; ++kt) {
    int cur = kt & 1;
    if (kt + 1 < nk) STAGE(kt + 1, cur ^ 1);
#pragma unroll
    for (int ks = 0; ks < 2; ++ks) {
      f16x8 af[4], bf[4];
      int rpos = ((ks * 4 + kb) ^ swr) * 8;
#pragma unroll
      for (int m = 0; m < 4; ++m)
        af[m] = *(const f16x8*)&As[cur][(wr * 64 + m * 16 + l15) * 64 + rpos];
#pragma unroll
      for (int n = 0; n < 4; ++n)
        bf[n] = *(const f16x8*)&Bs[cur][(wc * 64 + n * 16 + l15) * 64 + rpos];
#pragma unroll
      for (int m = 0; m < 4; ++m)
#pragma unroll
        for (int n = 0; n < 4; ++n)
          acc[m][n] = __builtin_amdgcn_mfma_f32_16x16x32_f16(af[m], bf[n], acc[m][n], 0, 0, 0);
    }
    __syncthreads();
  }
#pragma unroll
  for (int n = 0; n < 4; ++n) {
    int col = col0 + wc * 64 + n * 16 + l15;
    float bv = bias[col];
#pragma unroll
    for (int m = 0; m < 4; ++m) {
      int rowb = row0 + wr * 64 + m * 16 + kb * 4;
#pragma unroll
      for (int r = 0; r < 4; ++r) {
        float v = acc[m][n][r] + bv;
        if (OUT == 2) v = gelu_f(v);
        if (OUT == 3) v += (float)hres[(size_t)(rowb + r) * N + col];
        ((_Float16*)Cv)[(size_t)(rowb + r) * N + col] = (_Float16)v;
      }
    }
  }
}

// ---------------- f16 MFMA GEMM, BM=64 x BN=128, BK=64, 128 threads ---------
// Same 2-phase schedule/swizzle; 48KB LDS -> 3 blocks/CU. QKV (2304 blocks =
// 3 exact rounds) and N=768 GEMMs (768 blocks = 1 full round).
template <int OUT>
__global__ __launch_bounds__(128) void gemm64(
    const _Float16* __restrict__ A, const _Float16* __restrict__ Bt,
    const float* __restrict__ bias, void* __restrict__ Cv,
    int M, int N, int K, const _Float16* __restrict__ hres) {
  __shared__ _Float16 As[2][64 * 64];
  __shared__ _Float16 Bs[2][128 * 64];
  int tid = threadIdx.x;
  int lane = tid & 63, w = tid >> 6;  // w in {0,1}
  int l15 = lane & 15, kb = lane >> 4;
  int swr = l15 & 7;

  int nwg = gridDim.x * gridDim.y;
  int bid = blockIdx.y * gridDim.x + blockIdx.x;
  int swz = bid;
  if ((nwg & 7) == 0) {
    int cpx = nwg >> 3;
    swz = (bid & 7) * cpx + (bid >> 3);
  }
  int bx = swz % gridDim.x, by = swz / gridDim.x;
  int row0 = by * 64, col0 = bx * 128;

  int drow = lane >> 3;
  int schunk = (lane & 7) ^ drow;
  const _Float16* gA = A + (size_t)(row0 + w * 32 + drow) * K + schunk * 8;
  const _Float16* gB = Bt + (size_t)(col0 + w * 64 + drow) * K + schunk * 8;

  auto STAGE = [&](int t, int buf) {
    int ko = t * 64;
#pragma unroll
    for (int j = 0; j < 4; ++j)
      load_lds16(gA + (size_t)(j * 8) * K + ko,
                 (char*)&As[buf][0] + (w * 32 + j * 8) * 128);
#pragma unroll
    for (int j = 0; j < 8; ++j)
      load_lds16(gB + (size_t)(j * 8) * K + ko,
                 (char*)&Bs[buf][0] + (w * 64 + j * 8) * 128);
  };

  f32x4 acc[4][4] = {};
  int nk = K >> 6;

  STAGE(0, 0);
  __syncthreads();

  for (int kt = 0; kt < nk; ++kt) {
    int cur = kt & 1;
    if (kt + 1 < nk) STAGE(kt + 1, cur ^ 1);
#pragma unroll
    for (int ks = 0; ks < 2; ++ks) {
      f16x8 af[4], bf[4];
      int rpos = ((ks * 4 + kb) ^ swr) * 8;
#pragma unroll
      for (int m = 0; m < 4; ++m)
        af[m] = *(const f16x8*)&As[cur][(m * 16 + l15) * 64 + rpos];
#pragma unroll
      for (int n = 0; n < 4; ++n)
        bf[n] = *(const f16x8*)&Bs[cur][(w * 64 + n * 16 + l15) * 64 + rpos];
#pragma unroll
      for (int m = 0; m < 4; ++m)
#pragma unroll
        for (int n = 0; n < 4; ++n)
          acc[m][n] = __builtin_amdgcn_mfma_f32_16x16x32_f16(af[m], bf[n], acc[m][n], 0, 0, 0);
    }
    __syncthreads();
  }
#pragma unroll
  for (int n = 0; n < 4; ++n) {
    int col = col0 + w * 64 + n * 16 + l15;
    float bv = bias[col];
#pragma unroll
    for (int m = 0; m < 4; ++m) {
      int rowb = row0 + m * 16 + kb * 4;
#pragma unroll
      for (int r = 0; r < 4; ++r) {
        float v = acc[m][n][r] + bv;
        if (OUT == 2) v = gelu_f(v);
        if (OUT == 3) v += (float)hres[(size_t)(rowb + r) * N + col];
        ((_Float16*)Cv)[(size_t)(rowb + r) * N + col] = (_Float16)v;
      }
    }
  }
}

// ---------------- V transpose per head: qkv v-cols -> vt [b*12+h][64][512] --
__global__ __launch_bounds__(256) void vtrans_kernel(
    const _Float16* __restrict__ v, int RS, _Float16* __restrict__ vt) {
  __shared__ _Float16 T[64][72];
  int s0 = blockIdx.x * 64;
  int bh = blockIdx.y;
  int b = bh / NH_, h = bh % NH_;
  int tid = threadIdx.x;
#pragma unroll
  for (int i = 0; i < 2; ++i) {
    int chunk = tid + i * 256;
    int s = chunk >> 3, dc = (chunk & 7) * 8;
    *(f16x8*)&T[s][dc] = *(const f16x8*)&v[(size_t)(b * S_ + s0 + s) * RS + h * DH_ + dc];
  }
  __syncthreads();
#pragma unroll
  for (int i = 0; i < 2; ++i) {
    int chunk = tid + i * 256;
    int d = chunk >> 3, sc = (chunk & 7) * 8;
    f16x8 o;
#pragma unroll
    for (int j = 0; j < 8; ++j) o[j] = T[sc + j][d];
    *(f16x8*)&vt[(size_t)(bh * DH_ + d) * S_ + s0 + sc] = o;
  }
}

// ---------------- fused flash attention, f16 MFMA, paired q-tiles -----------
// grid (4 q-pairs, 12 heads, 16 batch) = 768 blocks. Two 64-row q-halves per
// block share the K/V staging. biasz staged in LDS as f16 (1KB): total LDS
// 54,272B <= 160KB/3 (3-block occupancy if VGPR permits; else == r13 config).
// f16 biasz is exact for mask=1 (0) and saturates to -inf for mask=0 -> exp2
// gives 0 = correct masking. T5 setprio around MFMA clusters.
__global__ __launch_bounds__(256) void flash_attn_kernel(
    const _Float16* __restrict__ q, const _Float16* __restrict__ k,
    const _Float16* __restrict__ vt, int RS, const float* __restrict__ biasz_g,
    _Float16* __restrict__ ctx) {
  __shared__ _Float16 Ks[128 * 72];
  __shared__ _Float16 Vs[64 * 136];
  __shared__ _Float16 Ps[4][16 * 136];
  __shared__ _Float16 biasz[S_];
  int qt = blockIdx.x, h = blockIdx.y, b = blockIdx.z;
  int tid = threadIdx.x, lane = tid & 63, w = tid >> 6;
  int l15 = lane & 15, kb = lane >> 4;
  const float C = 0.125f * 1.44269504088896f;

  for (int i = tid; i < S_; i += 256) biasz[i] = (_Float16)biasz_g[b * S_ + i];

  f16x8 qf[2][2];
#pragma unroll
  for (int hh = 0; hh < 2; ++hh) {
    int qrow = b * S_ + qt * 128 + hh * 64 + w * 16 + l15;
    qf[hh][0] = *(const f16x8*)&q[(size_t)qrow * RS + h * DH_ + kb * 8];
    qf[hh][1] = *(const f16x8*)&q[(size_t)qrow * RS + h * DH_ + 32 + kb * 8];
  }

  auto loadKV = [&](int kt, f16x8* rk, f16x8* rv) {
#pragma unroll
    for (int i = 0; i < 4; ++i) {
      int idx = tid + i * 256;
      int r = idx >> 3, c = idx & 7;
      rk[i] = *(const f16x8*)&k[(size_t)(b * S_ + kt * 128 + r) * RS + h * DH_ + c * 8];
      int d = idx >> 4, c2 = idx & 15;
      rv[i] = *(const f16x8*)&vt[(size_t)((b * NH_ + h) * DH_ + d) * S_ + kt * 128 + c2 * 8];
    }
  };

  float m_run[2][4], l_run[2][4];
  f32x4 o[2][4] = {};
#pragma unroll
  for (int hh = 0; hh < 2; ++hh)
#pragma unroll
    for (int r = 0; r < 4; ++r) { m_run[hh][r] = -1e30f; l_run[hh][r] = 0.f; }

  f16x8 rk[4], rv[4];
  loadKV(0, rk, rv);
  for (int kt = 0; kt < 4; ++kt) {
    __syncthreads();
#pragma unroll
    for (int i = 0; i < 4; ++i) {
      int idx = tid + i * 256;
      int r = idx >> 3, c = idx & 7;
      *(f16x8*)&Ks[r * 72 + c * 8] = rk[i];
      int d = idx >> 4, c2 = idx & 15;
      *(f16x8*)&Vs[d * 136 + c2 * 8] = rv[i];
    }
    __syncthreads();
    if (kt < 3) loadKV(kt + 1, rk, rv);
    float zb[8];
#pragma unroll
    for (int nf = 0; nf < 8; ++nf)
      zb[nf] = (float)biasz[kt * 128 + nf * 16 + l15];
#pragma unroll
    for (int hh = 0; hh < 2; ++hh) {
      f32x4 s[8];
      __builtin_amdgcn_s_setprio(1);
#pragma unroll
      for (int nf = 0; nf < 8; ++nf) {
        f16x8 b0 = *(const f16x8*)&Ks[(nf * 16 + l15) * 72 + kb * 8];
        f16x8 b1 = *(const f16x8*)&Ks[(nf * 16 + l15) * 72 + 32 + kb * 8];
        f32x4 z = {};
        z = __builtin_amdgcn_mfma_f32_16x16x32_f16(qf[hh][0], b0, z, 0, 0, 0);
        z = __builtin_amdgcn_mfma_f32_16x16x32_f16(qf[hh][1], b1, z, 0, 0, 0);
        s[nf] = z;
      }
      __builtin_amdgcn_s_setprio(0);
      float pw[8][4];
      float corr[4];
#pragma unroll
      for (int r = 0; r < 4; ++r) {
        float mx = -1e30f;
#pragma unroll
        for (int nf = 0; nf < 8; ++nf) mx = fmaxf(mx, s[nf][r] * C + zb[nf]);
#pragma unroll
        for (int d = 1; d < 16; d <<= 1) mx = fmaxf(mx, __shfl_xor(mx, d));
        float mnew = fmaxf(m_run[hh][r], mx);
        float cr = exp2f(m_run[hh][r] - mnew);
        m_run[hh][r] = mnew;
        corr[r] = cr;
        float sum = 0.f;
#pragma unroll
        for (int nf = 0; nf < 8; ++nf) {
          float pv = exp2f(s[nf][r] * C + zb[nf] - mnew);
          pw[nf][r] = pv;
          sum += pv;
        }
#pragma unroll
        for (int d = 1; d < 16; d <<= 1) sum += __shfl_xor(sum, d);
        l_run[hh][r] = l_run[hh][r] * cr + sum;
      }
#pragma unroll
      for (int nf2 = 0; nf2 < 4; ++nf2)
#pragma unroll
        for (int r = 0; r < 4; ++r) o[hh][nf2][r] *= corr[r];
#pragma unroll
      for (int nf = 0; nf < 8; ++nf)
#pragma unroll
        for (int r = 0; r < 4; ++r)
          Ps[w][(kb * 4 + r) * 136 + nf * 16 + l15] = (_Float16)pw[nf][r];
      // Ps is wave-private; within-wave ds write->read ordering handled by
      // compiler-inserted lgkmcnt waits.
      __builtin_amdgcn_s_setprio(1);
#pragma unroll
      for (int ks = 0; ks < 4; ++ks) {
        f16x8 pa = *(const f16x8*)&Ps[w][l15 * 136 + ks * 32 + kb * 8];
#pragma unroll
        for (int nf2 = 0; nf2 < 4; ++nf2) {
          f16x8 vb2 = *(const f16x8*)&Vs[(nf2 * 16 + l15) * 136 + ks * 32 + kb * 8];
          o[hh][nf2] = __builtin_amdgcn_mfma_f32_16x16x32_f16(pa, vb2, o[hh][nf2], 0, 0, 0);
        }
      }
      __builtin_amdgcn_s_setprio(0);
    }
  }
#pragma unroll
  for (int hh = 0; hh < 2; ++hh) {
    float inv[4];
#pragma unroll
    for (int r = 0; r < 4; ++r) inv[r] = 1.0f / fmaxf(l_run[hh][r], 1e-37f);
#pragma unroll
    for (int nf2 = 0; nf2 < 4; ++nf2)
#pragma unroll
      for (int r = 0; r < 4; ++r) {
        int row = b * S_ + qt * 128 + hh * 64 + w * 16 + kb * 4 + r;
        ctx[(size_t)row * H_ + h * DH_ + nf2 * 16 + l15] = (_Float16)(o[hh][nf2][r] * inv[r]);
      }
  }
}

// ---------------- valid-token compaction: parallel stable prefix scan -------
__global__ __launch_bounds__(512) void compact_idx_kernel(
    const int* __restrict__ valid, int* __restrict__ src_of) {
  __shared__ int wsum[8];
  int b = blockIdx.x;
  int t = threadIdx.x;
  int lane = t & 63, wv = t >> 6;
  int v = valid[b * S_ + t];
  unsigned long long ball = __ballot(v != 0);
  int pre = __popcll(ball & ((1ULL << lane) - 1ULL));
  if (lane == 0) wsum[wv] = __popcll(ball);
  src_of[b * S_ + t] = -1;  // fill; scatter below overwrites valid slots
  __syncthreads();
  int base = 0;
#pragma unroll
  for (int i = 0; i < 8; ++i) base += (i < wv) ? wsum[i] : 0;
  if (v) src_of[b * S_ + base + pre] = b * S_ + t;
}

// ---------------- classifier + softmax: one wave per output token -----------
__global__ __launch_bounds__(256) void cls_kernel(
    const _Float16* __restrict__ hb, const int* __restrict__ src_of,
    const float* __restrict__ W, const float* __restrict__ bias2,
    float* __restrict__ out) {
  int lane = threadIdx.x & 63, wv = threadIdx.x >> 6;
  int tok = blockIdx.x * 4 + wv;
  int src = src_of[tok];
  float acc[NL_] = {};
  if (src >= 0) {
    for (int h0 = lane * 2; h0 < H_; h0 += 128) {
      f16x2 xv = *(const f16x2*)&hb[(size_t)src * H_ + h0];
      float x0 = (float)xv[0], x1 = (float)xv[1];
#pragma unroll
      for (int n = 0; n < NL_; ++n)
        acc[n] = fmaf(x0, W[h0 * NL_ + n], fmaf(x1, W[(h0 + 1) * NL_ + n], acc[n]));
    }
  }
#pragma unroll
  for (int n = 0; n < NL_; ++n) {
#pragma unroll
    for (int off = 32; off; off >>= 1) acc[n] += __shfl_down(acc[n], off);
  }
  if (lane == 0) {
    float vls[NL_], mx = -1e30f;
#pragma unroll
    for (int n = 0; n < NL_; ++n) {
      vls[n] = acc[n] + bias2[n];
      mx = fmaxf(mx, vls[n]);
    }
    float s = 0.f;
#pragma unroll
    for (int n = 0; n < NL_; ++n) {
      vls[n] = expf(vls[n] - mx);
      s += vls[n];
    }
    float inv = 1.0f / s;
#pragma unroll
    for (int n = 0; n < NL_; ++n) out[(size_t)tok * NL_ + n] = vls[n] * inv;
  }
}

extern "C" void kernel_launch(void* const* d_in, const int* in_sizes, int n_in,
                              void* d_out, int out_size, void* d_ws, size_t ws_size,
                              hipStream_t stream) {
  const int* wid = (const int*)d_in[0];
  const int* mask = (const int*)d_in[1];
  const int* tpid = (const int*)d_in[2];
  const int* valid = (const int*)d_in[3];
  const float* we = (const float*)d_in[4];
  const float* pe = (const float*)d_in[5];
  const float* te = (const float*)d_in[6];
  const float* eg = (const float*)d_in[7];
  const float* eb = (const float*)d_in[8];
  const float* Wq = (const float*)d_in[9];
  const float* bq = (const float*)d_in[10];
  const float* Wk = (const float*)d_in[11];
  const float* bk = (const float*)d_in[12];
  const float* Wv = (const float*)d_in[13];
  const float* bv = (const float*)d_in[14];
  const float* Wo = (const float*)d_in[15];
  const float* bo = (const float*)d_in[16];
  const float* g1 = (const float*)d_in[17];
  const float* gb1 = (const float*)d_in[18];
  const float* W1 = (const float*)d_in[19];
  const float* bf1 = (const float*)d_in[20];
  const float* W2 = (const float*)d_in[21];
  const float* bf2 = (const float*)d_in[22];
  const float* g2 = (const float*)d_in[23];
  const float* gb2 = (const float*)d_in[24];
  const float* cW = (const float*)d_in[25];
  const float* cb = (const float*)d_in[26];
  float* out = (float*)d_out;

  const size_t TOK = (size_t)B_ * S_;  // 8192
  char* ws = (char*)d_ws;
  _Float16* hb = (_Float16*)(ws + 25165824);          // 12,582,912 B (residual stream)
  _Float16* t1h = (_Float16*)(ws + 37748736);         // 12,582,912 B (x = delta+res, f16)
  char* un1 = ws + 62914560;                          // 50,331,648 B union
  _Float16* qkv = (_Float16*)un1;                     // [8192][2304] = 37,748,736 B
  _Float16* vt = (_Float16*)(un1 + 37748736);         // 12,582,912 B
  _Float16* ffh = (_Float16*)un1;                     // overlays qkv/vt after attn
  _Float16* ctx = (_Float16*)(ws + 113246208);        // 12,582,912 B
  char* wbuf = ws + 125829120;                        // 14,155,776 B
  _Float16* wqT = (_Float16*)wbuf;                    // [2304][768] fused (q,k,v rows)
  _Float16* wkT = (_Float16*)(wbuf + 1179648);
  _Float16* wvT = (_Float16*)(wbuf + 2359296);
  _Float16* woT = (_Float16*)(wbuf + 3538944);
  _Float16* w1T = (_Float16*)(wbuf + 4718592);
  _Float16* w2T = (_Float16*)(wbuf + 9437184);
  int* src_of = (int*)(ws + 139984896);               // 32,768 B
  float* qkvb = (float*)(ws + 140017664);             // 9,216 B
  float* biasz_g = (float*)(ws + 140026880);          // 32,768 B

  dim3 blk(256);
  dim3 blk192(192);
  dim3 blk128(128);
  embed_ln_kernel<<<dim3((unsigned)TOK), blk, 0, stream>>>(wid, tpid, we, pe, te, eg, eb, hb);
  maskbias_kernel<<<dim3((unsigned)(TOK / 256)), blk, 0, stream>>>(mask, biasz_g);

  dim3 gQKV64(QKV_ / 128, TOK / 64);  // (18, 128) = 2304 blocks = 3 exact rounds @3/CU
  dim3 gH64(H_ / 128, TOK / 64);      // (6, 128)  = 768 blocks  = 1 round, all co-resident
  dim3 gF(FF_ / 128, TOK / 128);      // (24, 64)  = 1536 blocks = 3 exact rounds @2/CU
  for (int l = 0; l < L_; ++l) {
    convert_weights_kernel<<<dim3(1729), blk, 0, stream>>>(
        Wq + (size_t)l * H_ * H_, Wk + (size_t)l * H_ * H_,
        Wv + (size_t)l * H_ * H_, Wo + (size_t)l * H_ * H_,
        W1 + (size_t)l * H_ * FF_, W2 + (size_t)l * FF_ * H_,
        wqT, wkT, wvT, woT, w1T, w2T,
        bq + l * H_, bk + l * H_, bv + l * H_, qkvb);
    gemm64<1><<<gQKV64, blk128, 0, stream>>>(hb, wqT, qkvb, qkv, (int)TOK, QKV_, H_, nullptr);
    vtrans_kernel<<<dim3(S_ / 64, B_ * NH_), blk, 0, stream>>>(qkv + 2 * H_, QKV_, vt);
    flash_attn_kernel<<<dim3(S_ / 128, NH_, B_), blk, 0, stream>>>(
        qkv, qkv + H_, vt, QKV_, biasz_g, ctx);
    // x = ctx @ Wo + bo + hb  (f16)
    gemm64<3><<<gH64, blk128, 0, stream>>>(ctx, woT, bo + l * H_, t1h, (int)TOK, H_, H_, hb);
    ln_f16_kernel<<<dim3((unsigned)TOK), blk192, 0, stream>>>(t1h, g1 + l * H_, gb1 + l * H_, hb);
    gemm_f16<2><<<gF, blk, 0, stream>>>(hb, w1T, bf1 + l * FF_, ffh, (int)TOK, FF_, H_, nullptr);
    // x = ffh @ W2 + b2 + hb  (f16)
    gemm64<3><<<gH64, blk128, 0, stream>>>(ffh, w2T, bf2 + l * H_, t1h, (int)TOK, H_, FF_, hb);
    ln_f16_kernel<<<dim3((unsigned)TOK), blk192, 0, stream>>>(t1h, g2 + l * H_, gb2 + l * H_, hb);
  }

  compact_idx_kernel<<<dim3(B_), dim3(512), 0, stream>>>(valid, src_of);
  cls_kernel<<<dim3((unsigned)(TOK / 4)), blk, 0, stream>>>(hb, src_of, cW, cb, out);
}

// Round 16
// 3289.405 us; speedup vs baseline: 1.0091x; 1.0058x over previous
//
#include <hip/hip_runtime.h>
#include <cstdint>
#include <cstddef>

#define B_ 16
#define S_ 512
#define H_ 768
#define L_ 12
#define NH_ 12
#define DH_ 64
#define FF_ 3072
#define NL_ 9
#define QKV_ 2304

typedef _Float16 f16x8 __attribute__((ext_vector_type(8)));
typedef _Float16 f16x4 __attribute__((ext_vector_type(4)));
typedef _Float16 f16x2 __attribute__((ext_vector_type(2)));
typedef float f32x4 __attribute__((ext_vector_type(4)));

// ---------------- async global->LDS (16B per lane, wave-uniform LDS base) ---
__device__ __forceinline__ void load_lds16(const void* g, void* l) {
  __builtin_amdgcn_global_load_lds(
      (const __attribute__((address_space(1))) unsigned int*)g,
      (__attribute__((address_space(3))) unsigned int*)l, 16, 0, 0);
}

// ---------------- block reduction helpers ----------------
__device__ __forceinline__ float block_sum256(float v, float* red) {
#pragma unroll
  for (int off = 32; off; off >>= 1) v += __shfl_down(v, off);
  __syncthreads();
  if ((threadIdx.x & 63) == 0) red[threadIdx.x >> 6] = v;
  __syncthreads();
  return red[0] + red[1] + red[2] + red[3];
}

// 192-thread (3-wave) block sum
__device__ __forceinline__ float block_sum192(float v, float* red) {
#pragma unroll
  for (int off = 32; off; off >>= 1) v += __shfl_down(v, off);
  __syncthreads();
  if ((threadIdx.x & 63) == 0) red[threadIdx.x >> 6] = v;
  __syncthreads();
  return red[0] + red[1] + red[2];
}

// Fast exact-GELU: erf via Abramowitz-Stegun 7.1.26 (|err| < 1.5e-7).
__device__ __forceinline__ float gelu_f(float x) {
  float au = fabsf(x) * 0.70710678118654752f;
  float t = 1.0f / (1.0f + 0.3275911f * au);
  float p = ((((1.061405429f * t - 1.453152027f) * t + 1.421413741f) * t
              - 0.284496736f) * t + 0.254829592f) * t;
  float e = p * __expf(-au * au);
  float phi = (x >= 0.0f) ? (1.0f - 0.5f * e) : (0.5f * e);
  return x * phi;
}

// ---------------- embeddings + LayerNorm (writes f16 hb) --------------------
__global__ __launch_bounds__(256) void embed_ln_kernel(
    const int* __restrict__ wid, const int* __restrict__ tpid,
    const float* __restrict__ we, const float* __restrict__ pe,
    const float* __restrict__ te, const float* __restrict__ g,
    const float* __restrict__ bb, _Float16* __restrict__ hb) {
  __shared__ float red[4];
  int tok = blockIdx.x;
  int s = tok & (S_ - 1);
  int w = wid[tok], tp = tpid[tok];
  int t = threadIdx.x;
  float x[3];
#pragma unroll
  for (int i = 0; i < 3; ++i) {
    int j = t + i * 256;
    x[i] = we[(size_t)w * H_ + j] + pe[(size_t)s * H_ + j] + te[(size_t)tp * H_ + j];
  }
  float m = block_sum256(x[0] + x[1] + x[2], red) * (1.0f / H_);
  float d0 = x[0] - m, d1 = x[1] - m, d2 = x[2] - m;
  float var = block_sum256(d0 * d0 + d1 * d1 + d2 * d2, red) * (1.0f / H_);
  float rs = rsqrtf(var + 1e-12f);
#pragma unroll
  for (int i = 0; i < 3; ++i) {
    int j = t + i * 256;
    float v = (x[i] - m) * rs * g[j] + bb[j];
    hb[(size_t)tok * H_ + j] = (_Float16)v;
  }
}

// ---------------- pure LayerNorm on f16 x -> f16 hb (192 thr, f16x4) --------
__global__ __launch_bounds__(192) void ln_f16_kernel(
    const _Float16* __restrict__ x, const float* __restrict__ g,
    const float* __restrict__ bb, _Float16* __restrict__ hb) {
  __shared__ float red[3];
  int tok = blockIdx.x;
  int t = threadIdx.x;
  int j = t * 4;
  f16x4 xv = *(const f16x4*)&x[(size_t)tok * H_ + j];
  float v0 = (float)xv[0], v1 = (float)xv[1], v2 = (float)xv[2], v3 = (float)xv[3];
  float m = block_sum192(v0 + v1 + v2 + v3, red) * (1.0f / H_);
  float d0 = v0 - m, d1 = v1 - m, d2 = v2 - m, d3 = v3 - m;
  __syncthreads();  // red reuse
  float var = block_sum192(d0 * d0 + d1 * d1 + d2 * d2 + d3 * d3, red) * (1.0f / H_);
  float rs = rsqrtf(var + 1e-12f);
  float4 gv = *(const float4*)&g[j];
  float4 bv = *(const float4*)&bb[j];
  f16x4 o;
  o[0] = (_Float16)(d0 * rs * gv.x + bv.x);
  o[1] = (_Float16)(d1 * rs * gv.y + bv.y);
  o[2] = (_Float16)(d2 * rs * gv.z + bv.z);
  o[3] = (_Float16)(d3 * rs * gv.w + bv.w);
  *(f16x4*)&hb[(size_t)tok * H_ + j] = o;
}

// ---------------- per-layer weight convert + transpose: f32 [K][N] -> f16 [N][K]
// block 1728 additionally concats qkv bias. 64x64 tiles.
__global__ __launch_bounds__(256) void convert_weights_kernel(
    const float* __restrict__ Wq, const float* __restrict__ Wk,
    const float* __restrict__ Wv, const float* __restrict__ Wo,
    const float* __restrict__ W1, const float* __restrict__ W2,
    _Float16* __restrict__ qT, _Float16* __restrict__ kT,
    _Float16* __restrict__ vT, _Float16* __restrict__ oT,
    _Float16* __restrict__ w1T, _Float16* __restrict__ w2T,
    const float* __restrict__ bq, const float* __restrict__ bk,
    const float* __restrict__ bv, float* __restrict__ qkvb) {
  int id = blockIdx.x;
  int tid = threadIdx.x;
  if (id == 1728) {  // bias concat
    for (int j = tid; j < H_; j += 256) {
      qkvb[j] = bq[j];
      qkvb[H_ + j] = bk[j];
      qkvb[2 * H_ + j] = bv[j];
    }
    return;
  }
  __shared__ float T[64][65];
  const float* src;
  _Float16* dst;
  int K, N, tk, tn;
  if (id < 576) {
    int mat = id / 144, t = id % 144;
    K = 768; N = 768; tk = t / 12; tn = t % 12;
    src = (mat == 0) ? Wq : (mat == 1) ? Wk : (mat == 2) ? Wv : Wo;
    dst = (mat == 0) ? qT : (mat == 1) ? kT : (mat == 2) ? vT : oT;
  } else if (id < 1152) {
    int t = id - 576; K = 768; N = 3072; tk = t / 48; tn = t % 48;
    src = W1; dst = w1T;
  } else {
    int t = id - 1152; K = 3072; N = 768; tk = t / 12; tn = t % 12;
    src = W2; dst = w2T;
  }
  int k0 = tk * 64, n0 = tn * 64;
  {
    int r = tid >> 4, c4 = (tid & 15) * 4;
#pragma unroll
    for (int i = 0; i < 4; ++i) {
      float4 v = *(const float4*)&src[(size_t)(k0 + r + i * 16) * N + n0 + c4];
      T[r + i * 16][c4 + 0] = v.x;
      T[r + i * 16][c4 + 1] = v.y;
      T[r + i * 16][c4 + 2] = v.z;
      T[r + i * 16][c4 + 3] = v.w;
    }
  }
  __syncthreads();
#pragma unroll
  for (int i = 0; i < 2; ++i) {
    int chunk = tid + i * 256;
    int n = chunk >> 3, kc = (chunk & 7) * 8;
    f16x8 o;
#pragma unroll
    for (int j = 0; j < 8; ++j) o[j] = (_Float16)T[kc + j][n];
    *(f16x8*)&dst[(size_t)(n0 + n) * K + k0 + kc] = o;
  }
}

// ---------------- attn mask bias precompute (layer-invariant) ---------------
__global__ void maskbias_kernel(const int* __restrict__ mask, float* __restrict__ bz) {
  int i = blockIdx.x * 256 + threadIdx.x;
  const float C = 0.125f * 1.44269504088896f;
  bz[i] = (1.0f - (float)mask[i]) * (-1e9f * C);
}

// ---------------- f16 MFMA GEMM, 2-phase dbuf, BM=128, BK=64 (r9, proven) ---
// OUT: 1 = f16+bias, 2 = f16+bias+GELU, 3 = f16+bias+residual(hres f16)
template <int OUT>
__global__ __launch_bounds__(256) void gemm_f16(
    const _Float16* __restrict__ A, const _Float16* __restrict__ Bt,
    const float* __restrict__ bias, void* __restrict__ Cv,
    int M, int N, int K, const _Float16* __restrict__ hres) {
  __shared__ _Float16 As[2][128 * 64];
  __shared__ _Float16 Bs[2][128 * 64];
  int tid = threadIdx.x;
  int lane = tid & 63, w = tid >> 6;
  int wr = w >> 1, wc = w & 1;
  int l15 = lane & 15, kb = lane >> 4;
  int swr = l15 & 7;

  int nwg = gridDim.x * gridDim.y;
  int bid = blockIdx.y * gridDim.x + blockIdx.x;
  int swz = bid;
  if ((nwg & 7) == 0) {
    int cpx = nwg >> 3;
    swz = (bid & 7) * cpx + (bid >> 3);
  }
  int bx = swz % gridDim.x, by = swz / gridDim.x;
  int row0 = by * 128, col0 = bx * 128;

  int drow = lane >> 3;
  int schunk = (lane & 7) ^ drow;
  const _Float16* gA = A + (size_t)(row0 + w * 32 + drow) * K + schunk * 8;
  const _Float16* gB = Bt + (size_t)(col0 + w * 32 + drow) * K + schunk * 8;

  auto STAGE = [&](int t, int buf) {
    int ko = t * 64;
#pragma unroll
    for (int j = 0; j < 4; ++j) {
      load_lds16(gA + (size_t)(j * 8) * K + ko,
                 (char*)&As[buf][0] + (w * 32 + j * 8) * 128);
      load_lds16(gB + (size_t)(j * 8) * K + ko,
                 (char*)&Bs[buf][0] + (w * 32 + j * 8) * 128);
    }
  };

  f32x4 acc[4][4] = {};
  int nk = K >> 6;

  STAGE(0, 0);
  __syncthreads();

  for (int kt = 0; kt < nk; ++kt) {
    int cur = kt & 1;
    if (kt + 1 < nk) STAGE(kt + 1, cur ^ 1);
#pragma unroll
    for (int ks = 0; ks < 2; ++ks) {
      f16x8 af[4], bf[4];
      int rpos = ((ks * 4 + kb) ^ swr) * 8;
#pragma unroll
      for (int m = 0; m < 4; ++m)
        af[m] = *(const f16x8*)&As[cur][(wr * 64 + m * 16 + l15) * 64 + rpos];
#pragma unroll
      for (int n = 0; n < 4; ++n)
        bf[n] = *(const f16x8*)&Bs[cur][(wc * 64 + n * 16 + l15) * 64 + rpos];
#pragma unroll
      for (int m = 0; m < 4; ++m)
#pragma unroll
        for (int n = 0; n < 4; ++n)
          acc[m][n] = __builtin_amdgcn_mfma_f32_16x16x32_f16(af[m], bf[n], acc[m][n], 0, 0, 0);
    }
    __syncthreads();
  }
#pragma unroll
  for (int n = 0; n < 4; ++n) {
    int col = col0 + wc * 64 + n * 16 + l15;
    float bv = bias[col];
#pragma unroll
    for (int m = 0; m < 4; ++m) {
      int rowb = row0 + wr * 64 + m * 16 + kb * 4;
#pragma unroll
      for (int r = 0; r < 4; ++r) {
        float v = acc[m][n][r] + bv;
        if (OUT == 2) v = gelu_f(v);
        if (OUT == 3) v += (float)hres[(size_t)(rowb + r) * N + col];
        ((_Float16*)Cv)[(size_t)(rowb + r) * N + col] = (_Float16)v;
      }
    }
  }
}

// ---------------- f16 MFMA GEMM, BM=64 x BN=128, BK=64, 128 threads ---------
// Same 2-phase schedule/swizzle; 48KB LDS -> 3 blocks/CU. QKV (2304 blocks =
// 3 exact rounds) and N=768 GEMMs (768 blocks = 1 full round).
// OUT: 1 = f16+bias, 2 = +GELU, 3 = +residual, 4 = QKV mode (V columns
// [1536,2304) are written transposed into vtout; q/k columns as OUT=1).
template <int OUT>
__global__ __launch_bounds__(128) void gemm64(
    const _Float16* __restrict__ A, const _Float16* __restrict__ Bt,
    const float* __restrict__ bias, void* __restrict__ Cv,
    int M, int N, int K, const _Float16* __restrict__ hres,
    _Float16* __restrict__ vtout) {
  __shared__ _Float16 As[2][64 * 64];
  __shared__ _Float16 Bs[2][128 * 64];
  int tid = threadIdx.x;
  int lane = tid & 63, w = tid >> 6;  // w in {0,1}
  int l15 = lane & 15, kb = lane >> 4;
  int swr = l15 & 7;

  int nwg = gridDim.x * gridDim.y;
  int bid = blockIdx.y * gridDim.x + blockIdx.x;
  int swz = bid;
  if ((nwg & 7) == 0) {
    int cpx = nwg >> 3;
    swz = (bid & 7) * cpx + (bid >> 3);
  }
  int bx = swz % gridDim.x, by = swz / gridDim.x;
  int row0 = by * 64, col0 = bx * 128;

  int drow = lane >> 3;
  int schunk = (lane & 7) ^ drow;
  const _Float16* gA = A + (size_t)(row0 + w * 32 + drow) * K + schunk * 8;
  const _Float16* gB = Bt + (size_t)(col0 + w * 64 + drow) * K + schunk * 8;

  auto STAGE = [&](int t, int buf) {
    int ko = t * 64;
#pragma unroll
    for (int j = 0; j < 4; ++j)
      load_lds16(gA + (size_t)(j * 8) * K + ko,
                 (char*)&As[buf][0] + (w * 32 + j * 8) * 128);
#pragma unroll
    for (int j = 0; j < 8; ++j)
      load_lds16(gB + (size_t)(j * 8) * K + ko,
                 (char*)&Bs[buf][0] + (w * 64 + j * 8) * 128);
  };

  f32x4 acc[4][4] = {};
  int nk = K >> 6;

  STAGE(0, 0);
  __syncthreads();

  for (int kt = 0; kt < nk; ++kt) {
    int cur = kt & 1;
    if (kt + 1 < nk) STAGE(kt + 1, cur ^ 1);
#pragma unroll
    for (int ks = 0; ks < 2; ++ks) {
      f16x8 af[4], bf[4];
      int rpos = ((ks * 4 + kb) ^ swr) * 8;
#pragma unroll
      for (int m = 0; m < 4; ++m)
        af[m] = *(const f16x8*)&As[cur][(m * 16 + l15) * 64 + rpos];
#pragma unroll
      for (int n = 0; n < 4; ++n)
        bf[n] = *(const f16x8*)&Bs[cur][(w * 64 + n * 16 + l15) * 64 + rpos];
#pragma unroll
      for (int m = 0; m < 4; ++m)
#pragma unroll
        for (int n = 0; n < 4; ++n)
          acc[m][n] = __builtin_amdgcn_mfma_f32_16x16x32_f16(af[m], bf[n], acc[m][n], 0, 0, 0);
    }
    __syncthreads();
  }
#pragma unroll
  for (int n = 0; n < 4; ++n) {
    int col = col0 + w * 64 + n * 16 + l15;
    float bv = bias[col];
#pragma unroll
    for (int m = 0; m < 4; ++m) {
      int rowb = row0 + m * 16 + kb * 4;
      if (OUT == 4 && col >= 1536) {
        // V column: write transposed into vt [b*12+h][64 d][512 s].
        // 4 consecutive rows = 4 consecutive s -> one f16x4 store.
        int hh = (col - 1536) >> 6, d = (col - 1536) & 63;
        int s0 = rowb & (S_ - 1), bbat = row0 >> 9;
        f16x4 o4;
#pragma unroll
        for (int r = 0; r < 4; ++r) o4[r] = (_Float16)(acc[m][n][r] + bv);
        *(f16x4*)&vtout[((size_t)(bbat * NH_ + hh) * DH_ + d) * S_ + s0] = o4;
      } else {
#pragma unroll
        for (int r = 0; r < 4; ++r) {
          float v = acc[m][n][r] + bv;
          if (OUT == 2) v = gelu_f(v);
          if (OUT == 3) v += (float)hres[(size_t)(rowb + r) * N + col];
          ((_Float16*)Cv)[(size_t)(rowb + r) * N + col] = (_Float16)v;
        }
      }
    }
  }
}

// ---------------- fused flash attention, f16 MFMA, paired q-tiles -----------
// grid (4 q-pairs, 12 heads, 16 batch) = 768 blocks. Two 64-row q-halves per
// block share the K/V staging. biasz staged in LDS as f16 (exact for mask=1;
// saturates to -inf for mask=0 -> exp2 gives 0 = correct masking).
__global__ __launch_bounds__(256) void flash_attn_kernel(
    const _Float16* __restrict__ q, const _Float16* __restrict__ k,
    const _Float16* __restrict__ vt, int RS, const float* __restrict__ biasz_g,
    _Float16* __restrict__ ctx) {
  __shared__ _Float16 Ks[128 * 72];
  __shared__ _Float16 Vs[64 * 136];
  __shared__ _Float16 Ps[4][16 * 136];
  __shared__ _Float16 biasz[S_];
  int qt = blockIdx.x, h = blockIdx.y, b = blockIdx.z;
  int tid = threadIdx.x, lane = tid & 63, w = tid >> 6;
  int l15 = lane & 15, kb = lane >> 4;
  const float C = 0.125f * 1.44269504088896f;

  for (int i = tid; i < S_; i += 256) biasz[i] = (_Float16)biasz_g[b * S_ + i];

  f16x8 qf[2][2];
#pragma unroll
  for (int hh = 0; hh < 2; ++hh) {
    int qrow = b * S_ + qt * 128 + hh * 64 + w * 16 + l15;
    qf[hh][0] = *(const f16x8*)&q[(size_t)qrow * RS + h * DH_ + kb * 8];
    qf[hh][1] = *(const f16x8*)&q[(size_t)qrow * RS + h * DH_ + 32 + kb * 8];
  }

  auto loadKV = [&](int kt, f16x8* rk, f16x8* rv) {
#pragma unroll
    for (int i = 0; i < 4; ++i) {
      int idx = tid + i * 256;
      int r = idx >> 3, c = idx & 7;
      rk[i] = *(const f16x8*)&k[(size_t)(b * S_ + kt * 128 + r) * RS + h * DH_ + c * 8];
      int d = idx >> 4, c2 = idx & 15;
      rv[i] = *(const f16x8*)&vt[(size_t)((b * NH_ + h) * DH_ + d) * S_ + kt * 128 + c2 * 8];
    }
  };

  float m_run[2][4], l_run[2][4];
  f32x4 o[2][4] = {};
#pragma unroll
  for (int hh = 0; hh < 2; ++hh)
#pragma unroll
    for (int r = 0; r < 4; ++r) { m_run[hh][r] = -1e30f; l_run[hh][r] = 0.f; }

  f16x8 rk[4], rv[4];
  loadKV(0, rk, rv);
  for (int kt = 0; kt < 4; ++kt) {
    __syncthreads();
#pragma unroll
    for (int i = 0; i < 4; ++i) {
      int idx = tid + i * 256;
      int r = idx >> 3, c = idx & 7;
      *(f16x8*)&Ks[r * 72 + c * 8] = rk[i];
      int d = idx >> 4, c2 = idx & 15;
      *(f16x8*)&Vs[d * 136 + c2 * 8] = rv[i];
    }
    __syncthreads();
    if (kt < 3) loadKV(kt + 1, rk, rv);
    float zb[8];
#pragma unroll
    for (int nf = 0; nf < 8; ++nf)
      zb[nf] = (float)biasz[kt * 128 + nf * 16 + l15];
#pragma unroll
    for (int hh = 0; hh < 2; ++hh) {
      f32x4 s[8];
      __builtin_amdgcn_s_setprio(1);
#pragma unroll
      for (int nf = 0; nf < 8; ++nf) {
        f16x8 b0 = *(const f16x8*)&Ks[(nf * 16 + l15) * 72 + kb * 8];
        f16x8 b1 = *(const f16x8*)&Ks[(nf * 16 + l15) * 72 + 32 + kb * 8];
        f32x4 z = {};
        z = __builtin_amdgcn_mfma_f32_16x16x32_f16(qf[hh][0], b0, z, 0, 0, 0);
        z = __builtin_amdgcn_mfma_f32_16x16x32_f16(qf[hh][1], b1, z, 0, 0, 0);
        s[nf] = z;
      }
      __builtin_amdgcn_s_setprio(0);
      float pw[8][4];
      float corr[4];
#pragma unroll
      for (int r = 0; r < 4; ++r) {
        float mx = -1e30f;
#pragma unroll
        for (int nf = 0; nf < 8; ++nf) mx = fmaxf(mx, s[nf][r] * C + zb[nf]);
#pragma unroll
        for (int d = 1; d < 16; d <<= 1) mx = fmaxf(mx, __shfl_xor(mx, d));
        float mnew = fmaxf(m_run[hh][r], mx);
        float cr = exp2f(m_run[hh][r] - mnew);
        m_run[hh][r] = mnew;
        corr[r] = cr;
        float sum = 0.f;
#pragma unroll
        for (int nf = 0; nf < 8; ++nf) {
          float pv = exp2f(s[nf][r] * C + zb[nf] - mnew);
          pw[nf][r] = pv;
          sum += pv;
        }
#pragma unroll
        for (int d = 1; d < 16; d <<= 1) sum += __shfl_xor(sum, d);
        l_run[hh][r] = l_run[hh][r] * cr + sum;
      }
#pragma unroll
      for (int nf2 = 0; nf2 < 4; ++nf2)
#pragma unroll
        for (int r = 0; r < 4; ++r) o[hh][nf2][r] *= corr[r];
#pragma unroll
      for (int nf = 0; nf < 8; ++nf)
#pragma unroll
        for (int r = 0; r < 4; ++r)
          Ps[w][(kb * 4 + r) * 136 + nf * 16 + l15] = (_Float16)pw[nf][r];
      // Ps is wave-private; within-wave ds write->read ordering handled by
      // compiler-inserted lgkmcnt waits.
      __builtin_amdgcn_s_setprio(1);
#pragma unroll
      for (int ks = 0; ks < 4; ++ks) {
        f16x8 pa = *(const f16x8*)&Ps[w][l15 * 136 + ks * 32 + kb * 8];
#pragma unroll
        for (int nf2 = 0; nf2 < 4; ++nf2) {
          f16x8 vb2 = *(const f16x8*)&Vs[(nf2 * 16 + l15) * 136 + ks * 32 + kb * 8];
          o[hh][nf2] = __builtin_amdgcn_mfma_f32_16x16x32_f16(pa, vb2, o[hh][nf2], 0, 0, 0);
        }
      }
      __builtin_amdgcn_s_setprio(0);
    }
  }
#pragma unroll
  for (int hh = 0; hh < 2; ++hh) {
    float inv[4];
#pragma unroll
    for (int r = 0; r < 4; ++r) inv[r] = 1.0f / fmaxf(l_run[hh][r], 1e-37f);
#pragma unroll
    for (int nf2 = 0; nf2 < 4; ++nf2)
#pragma unroll
      for (int r = 0; r < 4; ++r) {
        int row = b * S_ + qt * 128 + hh * 64 + w * 16 + kb * 4 + r;
        ctx[(size_t)row * H_ + h * DH_ + nf2 * 16 + l15] = (_Float16)(o[hh][nf2][r] * inv[r]);
      }
  }
}

// ---------------- valid-token compaction: parallel stable prefix scan -------
__global__ __launch_bounds__(512) void compact_idx_kernel(
    const int* __restrict__ valid, int* __restrict__ src_of) {
  __shared__ int wsum[8];
  int b = blockIdx.x;
  int t = threadIdx.x;
  int lane = t & 63, wv = t >> 6;
  int v = valid[b * S_ + t];
  unsigned long long ball = __ballot(v != 0);
  int pre = __popcll(ball & ((1ULL << lane) - 1ULL));
  if (lane == 0) wsum[wv] = __popcll(ball);
  src_of[b * S_ + t] = -1;  // fill; scatter below overwrites valid slots
  __syncthreads();
  int base = 0;
#pragma unroll
  for (int i = 0; i < 8; ++i) base += (i < wv) ? wsum[i] : 0;
  if (v) src_of[b * S_ + base + pre] = b * S_ + t;
}

// ---------------- classifier + softmax: one wave per output token -----------
__global__ __launch_bounds__(256) void cls_kernel(
    const _Float16* __restrict__ hb, const int* __restrict__ src_of,
    const float* __restrict__ W, const float* __restrict__ bias2,
    float* __restrict__ out) {
  int lane = threadIdx.x & 63, wv = threadIdx.x >> 6;
  int tok = blockIdx.x * 4 + wv;
  int src = src_of[tok];
  float acc[NL_] = {};
  if (src >= 0) {
    for (int h0 = lane * 2; h0 < H_; h0 += 128) {
      f16x2 xv = *(const f16x2*)&hb[(size_t)src * H_ + h0];
      float x0 = (float)xv[0], x1 = (float)xv[1];
#pragma unroll
      for (int n = 0; n < NL_; ++n)
        acc[n] = fmaf(x0, W[h0 * NL_ + n], fmaf(x1, W[(h0 + 1) * NL_ + n], acc[n]));
    }
  }
#pragma unroll
  for (int n = 0; n < NL_; ++n) {
#pragma unroll
    for (int off = 32; off; off >>= 1) acc[n] += __shfl_down(acc[n], off);
  }
  if (lane == 0) {
    float vls[NL_], mx = -1e30f;
#pragma unroll
    for (int n = 0; n < NL_; ++n) {
      vls[n] = acc[n] + bias2[n];
      mx = fmaxf(mx, vls[n]);
    }
    float s = 0.f;
#pragma unroll
    for (int n = 0; n < NL_; ++n) {
      vls[n] = expf(vls[n] - mx);
      s += vls[n];
    }
    float inv = 1.0f / s;
#pragma unroll
    for (int n = 0; n < NL_; ++n) out[(size_t)tok * NL_ + n] = vls[n] * inv;
  }
}

extern "C" void kernel_launch(void* const* d_in, const int* in_sizes, int n_in,
                              void* d_out, int out_size, void* d_ws, size_t ws_size,
                              hipStream_t stream) {
  const int* wid = (const int*)d_in[0];
  const int* mask = (const int*)d_in[1];
  const int* tpid = (const int*)d_in[2];
  const int* valid = (const int*)d_in[3];
  const float* we = (const float*)d_in[4];
  const float* pe = (const float*)d_in[5];
  const float* te = (const float*)d_in[6];
  const float* eg = (const float*)d_in[7];
  const float* eb = (const float*)d_in[8];
  const float* Wq = (const float*)d_in[9];
  const float* bq = (const float*)d_in[10];
  const float* Wk = (const float*)d_in[11];
  const float* bk = (const float*)d_in[12];
  const float* Wv = (const float*)d_in[13];
  const float* bv = (const float*)d_in[14];
  const float* Wo = (const float*)d_in[15];
  const float* bo = (const float*)d_in[16];
  const float* g1 = (const float*)d_in[17];
  const float* gb1 = (const float*)d_in[18];
  const float* W1 = (const float*)d_in[19];
  const float* bf1 = (const float*)d_in[20];
  const float* W2 = (const float*)d_in[21];
  const float* bf2 = (const float*)d_in[22];
  const float* g2 = (const float*)d_in[23];
  const float* gb2 = (const float*)d_in[24];
  const float* cW = (const float*)d_in[25];
  const float* cb = (const float*)d_in[26];
  float* out = (float*)d_out;

  const size_t TOK = (size_t)B_ * S_;  // 8192
  char* ws = (char*)d_ws;
  _Float16* hb = (_Float16*)(ws + 25165824);          // 12,582,912 B (residual stream)
  _Float16* t1h = (_Float16*)(ws + 37748736);         // 12,582,912 B (x = delta+res, f16)
  char* un1 = ws + 62914560;                          // 50,331,648 B union
  _Float16* qkv = (_Float16*)un1;                     // [8192][2304] = 37,748,736 B
  _Float16* vt = (_Float16*)(un1 + 37748736);         // 12,582,912 B
  _Float16* ffh = (_Float16*)un1;                     // overlays qkv/vt after attn
  _Float16* ctx = (_Float16*)(ws + 113246208);        // 12,582,912 B
  char* wbuf = ws + 125829120;                        // 14,155,776 B
  _Float16* wqT = (_Float16*)wbuf;                    // [2304][768] fused (q,k,v rows)
  _Float16* wkT = (_Float16*)(wbuf + 1179648);
  _Float16* wvT = (_Float16*)(wbuf + 2359296);
  _Float16* woT = (_Float16*)(wbuf + 3538944);
  _Float16* w1T = (_Float16*)(wbuf + 4718592);
  _Float16* w2T = (_Float16*)(wbuf + 9437184);
  int* src_of = (int*)(ws + 139984896);               // 32,768 B
  float* qkvb = (float*)(ws + 140017664);             // 9,216 B
  float* biasz_g = (float*)(ws + 140026880);          // 32,768 B

  dim3 blk(256);
  dim3 blk192(192);
  dim3 blk128(128);
  embed_ln_kernel<<<dim3((unsigned)TOK), blk, 0, stream>>>(wid, tpid, we, pe, te, eg, eb, hb);
  maskbias_kernel<<<dim3((unsigned)(TOK / 256)), blk, 0, stream>>>(mask, biasz_g);

  dim3 gQKV64(QKV_ / 128, TOK / 64);  // (18, 128) = 2304 blocks = 3 exact rounds @3/CU
  dim3 gH64(H_ / 128, TOK / 64);      // (6, 128)  = 768 blocks  = 1 round, all co-resident
  dim3 gF(FF_ / 128, TOK / 128);      // (24, 64)  = 1536 blocks = 3 exact rounds @2/CU
  for (int l = 0; l < L_; ++l) {
    convert_weights_kernel<<<dim3(1729), blk, 0, stream>>>(
        Wq + (size_t)l * H_ * H_, Wk + (size_t)l * H_ * H_,
        Wv + (size_t)l * H_ * H_, Wo + (size_t)l * H_ * H_,
        W1 + (size_t)l * H_ * FF_, W2 + (size_t)l * FF_ * H_,
        wqT, wkT, wvT, woT, w1T, w2T,
        bq + l * H_, bk + l * H_, bv + l * H_, qkvb);
    // QKV: q,k written row-major into qkv; V columns written transposed to vt.
    gemm64<4><<<gQKV64, blk128, 0, stream>>>(hb, wqT, qkvb, qkv, (int)TOK, QKV_, H_,
                                             nullptr, vt);
    flash_attn_kernel<<<dim3(S_ / 128, NH_, B_), blk, 0, stream>>>(
        qkv, qkv + H_, vt, QKV_, biasz_g, ctx);
    // x = ctx @ Wo + bo + hb  (f16)
    gemm64<3><<<gH64, blk128, 0, stream>>>(ctx, woT, bo + l * H_, t1h, (int)TOK, H_, H_,
                                           hb, nullptr);
    ln_f16_kernel<<<dim3((unsigned)TOK), blk192, 0, stream>>>(t1h, g1 + l * H_, gb1 + l * H_, hb);
    gemm_f16<2><<<gF, blk, 0, stream>>>(hb, w1T, bf1 + l * FF_, ffh, (int)TOK, FF_, H_, nullptr);
    // x = ffh @ W2 + b2 + hb  (f16)
    gemm64<3><<<gH64, blk128, 0, stream>>>(ffh, w2T, bf2 + l * H_, t1h, (int)TOK, H_, FF_,
                                           hb, nullptr);
    ln_f16_kernel<<<dim3((unsigned)TOK), blk192, 0, stream>>>(t1h, g2 + l * H_, gb2 + l * H_, hb);
  }

  compact_idx_kernel<<<dim3(B_), dim3(512), 0, stream>>>(valid, src_of);
  cls_kernel<<<dim3((unsigned)(TOK / 4)), blk, 0, stream>>>(hb, src_of, cW, cb, out);
}